// Round 4
// baseline (108.368 us; speedup 1.0000x reference)
//
#include <hip/hip_runtime.h>
#include <hip/hip_bf16.h>
#include <hip/hip_fp16.h>

#define NOUT 50000
#define KNB 32            // neighbors per output point
#define CIN 16
#define COUT 32
#define NTAP 64
#define GP 16             // points per block (2 per wave, 8 waves)
#define ROW2B 2064        // bytes per point row in s_bl: 64*16*2 (bf16) + 16 pad
                          // (stride/4 = 516 == 4 mod 32 -> phase-3 reads 2-way/broadcast)

typedef __attribute__((ext_vector_type(8))) short short8;
typedef __attribute__((ext_vector_type(4))) float f32x4;

__device__ __forceinline__ unsigned int pk2(float lo, float hi) {
  // two f32 -> packed bf16x2 (RNE), lo -> bits[15:0]
  union { __hip_bfloat162 h2; unsigned int u; } cv;
  cv.h2 = __float22bfloat162_rn(make_float2(lo, hi));
  return cv.u;
}
__device__ __forceinline__ unsigned int pkh(float lo, float hi) {
  // two f32 -> packed f16x2 (RNE)
  union { __half2 h; unsigned int u; } cv;
  cv.h = __floats2half2_rn(lo, hi);
  return cv.u;
}
__device__ __forceinline__ unsigned int f2bf(float f) {
  unsigned int u = __float_as_uint(f);
  return (u + 0x7fffu + ((u >> 16) & 1u)) >> 16;
}

// Wf[s][g][n][j] = bf16(W[kc = s*32 + g*8 + j][n]) : GEMM2 B-frag order
__global__ void prep_w_kernel(const float* __restrict__ kern,
                              unsigned short* __restrict__ wf) {
  int idx = blockIdx.x * 256 + threadIdx.x;
  if (idx >= NTAP * CIN * COUT) return;  // 32768
  int j = idx & 7;
  int n = (idx >> 3) & 31;
  int g = (idx >> 8) & 3;
  int s = idx >> 10;
  int kc = s * 32 + g * 8 + j;
  wf[idx] = (unsigned short)f2bf(kern[kc * COUT + n]);
}

__launch_bounds__(512)
__global__ void cconv_kernel(const float* __restrict__ feats,
                             const float* __restrict__ inp_points,
                             const float* __restrict__ out_points,
                             const float* __restrict__ out_extents,
                             const float* __restrict__ scale_compat,
                             const int* __restrict__ nidx,
                             const float* __restrict__ ndist,
                             const unsigned short* __restrict__ wf,
                             const float* __restrict__ bias,
                             float* __restrict__ out) {
  // bf16 B matrix; element (t,c) of point p at byte p*ROW2B + t*32 + c*2
  __shared__ __align__(16) char s_bl[GP * ROW2B];          // 33024 B
  __shared__ uint2 s_edp[GP * KNB];                        // 4096 B f16x2 (tx,ty),(tz,imp)
  __shared__ float s_cacc[GP][COUT];                       // 2048 B
  __shared__ float s_den[GP];                              // 64 B

  const int tid = threadIdx.x;
  const int wv = tid >> 6;
  const int lane = tid & 63;

  ((float*)s_cacc)[tid] = 0.0f;   // blockDim == GP*COUT == 512 exactly

  // ---- phase 1: geometry; all 64 lanes active (2 points per wave) ----
  {
    const int h = lane >> 5;          // which of the wave's 2 points
    const int e = lane & 31;          // edge
    const int p = wv * 2 + h;         // point-in-block
    const int pg = blockIdx.x * GP + p;
    const int eg = pg * KNB + e;
    const int nb = nidx[eg];
    const float d = ndist[eg];
    float q = 1.0f - d * d;
    float w6 = q * q * q;
    w6 = fminf(fmaxf(w6, 0.0f), 1.0f);
    const float imp = scale_compat[eg] * w6;

    const float inv = 1.0f / (0.5f * out_extents[pg]);
    const float rx = (inp_points[nb * 3 + 0] - out_points[pg * 3 + 0]) * inv;
    const float ry = (inp_points[nb * 3 + 1] - out_points[pg * 3 + 1]) * inv;
    const float rz = (inp_points[nb * 3 + 2] - out_points[pg * 3 + 2]) * inv;
    const float r = sqrtf(rx * rx + ry * ry + rz * rz);
    const float linf = fmaxf(fabsf(rx), fmaxf(fabsf(ry), fabsf(rz)));
    const float sf = r / fmaxf(linf, 1e-12f);
    const float tx = fminf(fmaxf((rx * sf * 0.5f + 0.5f) * 3.0f, 0.0f), 3.0f);
    const float ty = fminf(fmaxf((ry * sf * 0.5f + 0.5f) * 3.0f, 0.0f), 3.0f);
    const float tz = fminf(fmaxf((rz * sf * 0.5f + 0.5f) * 3.0f, 0.0f), 3.0f);

    s_edp[p * KNB + e] = make_uint2(pkh(tx, ty), pkh(tz, imp));

    float dsum = imp;                 // reduce within each 32-lane half
#pragma unroll
    for (int m = 1; m < 32; m <<= 1) dsum += __shfl_xor(dsum, m);
    if (e == 0) s_den[p] = dsum;
  }
  // NO barrier: phase 2 reads only this wave's own s_edp rows (same-wave LDS
  // ops execute in order).

  // ---- phase 2: per-point GEMM1, transposed: D1T(16c x 64t) = Fe^T * W^T.
  // A-frag = Fe^T (row=chan), B-frag = W^T (col=tap); D lane holds 4
  // consecutive CHANNELS of one tap -> direct bf16 packing, no shuffles. ----
  {
    const int c = lane & 15;          // chan (A row) == tap-in-tile (B col)
    const int g = lane >> 4;          // edge group: edges 8g..8g+7
    const float kyf = (float)(c >> 2);
    const float kzf = (float)(c & 3);
#pragma unroll
    for (int h = 0; h < 2; ++h) {
      const int p = wv * 2 + h;
      const int pg = blockIdx.x * GP + p;
      union { unsigned int u[4]; short8 v; } wfr0, wfr1, wfr2, wfr3, fef;
      float wprev0, wprev1, wprev2, wprev3, feprev;
#pragma unroll
      for (int j = 0; j < 8; ++j) {
        const uint2 ep = s_edp[p * KNB + g * 8 + j];
        union { unsigned int u; __half2 h2; } ua, ub;
        ua.u = ep.x; ub.u = ep.y;
        const float tx = __low2float(ua.h2), ty = __high2float(ua.h2);
        const float tz = __low2float(ub.h2), im = __high2float(ub.h2);
        const int nb = nidx[pg * KNB + g * 8 + j];
        const float f = feats[nb * CIN + c];
        const float hy = fmaxf(0.0f, 1.0f - fabsf(ty - kyf));
        const float hz = fmaxf(0.0f, 1.0f - fabsf(tz - kzf));
        const float m = hy * hz * im;
        const float w0 = fmaxf(0.0f, 1.0f - tx) * m;            // tx >= 0
        const float w1 = fmaxf(0.0f, 1.0f - fabsf(tx - 1.0f)) * m;
        const float w2 = fmaxf(0.0f, 1.0f - fabsf(tx - 2.0f)) * m;
        const float w3 = fmaxf(0.0f, tx - 2.0f) * m;            // tx <= 3
        if (j & 1) {
          wfr0.u[j >> 1] = pk2(wprev0, w0);
          wfr1.u[j >> 1] = pk2(wprev1, w1);
          wfr2.u[j >> 1] = pk2(wprev2, w2);
          wfr3.u[j >> 1] = pk2(wprev3, w3);
          fef.u[j >> 1] = pk2(feprev, f);
        } else {
          wprev0 = w0; wprev1 = w1; wprev2 = w2; wprev3 = w3; feprev = f;
        }
      }
      const f32x4 z = {0.f, 0.f, 0.f, 0.f};
      f32x4 d0 = __builtin_amdgcn_mfma_f32_16x16x32_bf16(fef.v, wfr0.v, z, 0, 0, 0);
      f32x4 d1 = __builtin_amdgcn_mfma_f32_16x16x32_bf16(fef.v, wfr1.v, z, 0, 0, 0);
      f32x4 d2 = __builtin_amdgcn_mfma_f32_16x16x32_bf16(fef.v, wfr2.v, z, 0, 0, 0);
      f32x4 d3 = __builtin_amdgcn_mfma_f32_16x16x32_bf16(fef.v, wfr3.v, z, 0, 0, 0);
      // lane holds chans {4g..4g+3} of tap (tile*16 + c); byte = t*32 + chan*2
      char* bp = s_bl + (unsigned)(p * ROW2B + c * 32 + g * 8);
      *(uint2*)(bp + 0 * 512) = make_uint2(pk2(d0[0], d0[1]), pk2(d0[2], d0[3]));
      *(uint2*)(bp + 1 * 512) = make_uint2(pk2(d1[0], d1[1]), pk2(d1[2], d1[3]));
      *(uint2*)(bp + 2 * 512) = make_uint2(pk2(d2[0], d2[1]), pk2(d2[2], d2[3]));
      *(uint2*)(bp + 3 * 512) = make_uint2(pk2(d3[0], d3[1]), pk2(d3[2], d3[3]));
    }
  }

  __syncthreads();

  // ---- phase 3: GEMM2. M = 16 points (all valid), N = 32, K = 1024 over
  // 8 waves (4 ksteps of 32 each); A-frag is a raw b128 bf16 read. ----
  f32x4 acc0 = {0.f, 0.f, 0.f, 0.f}, acc1 = {0.f, 0.f, 0.f, 0.f};
  const int pl = lane & 15;   // A row = point; B col = cout
  const int g4 = lane >> 4;
#pragma unroll
  for (int ss = 0; ss < 4; ++ss) {
    const int s = wv * 4 + ss;
    const short8 a = *(const short8*)(s_bl + pl * ROW2B + s * 64 + g4 * 16);
    const short8 b0 = *(const short8*)(wf + ((unsigned)((s * 4 + g4) * 32) + pl) * 8);
    const short8 b1 = *(const short8*)(wf + ((unsigned)((s * 4 + g4) * 32) + 16 + pl) * 8);
    acc0 = __builtin_amdgcn_mfma_f32_16x16x32_bf16(a, b0, acc0, 0, 0, 0);
    acc1 = __builtin_amdgcn_mfma_f32_16x16x32_bf16(a, b1, acc1, 0, 0, 0);
  }
#pragma unroll
  for (int j = 0; j < 4; ++j) {
    const int row = g4 * 4 + j;    // D row = point, all 16 valid
    atomicAdd(&s_cacc[row][pl], acc0[j]);
    atomicAdd(&s_cacc[row][pl + 16], acc1[j]);
  }

  __syncthreads();

  // ---- epilogue: normalize, bias, relu; 512 threads == 512 outputs ----
  {
    const int p = tid >> 5;
    const int dch = tid & 31;
    const float den = s_den[p];
    float v = ((float*)s_cacc)[tid] / (den > 0.0f ? den : 1.0f) + bias[dch];
    out[blockIdx.x * (GP * COUT) + tid] = fmaxf(v, 0.0f);
  }
}

extern "C" void kernel_launch(void* const* d_in, const int* in_sizes, int n_in,
                              void* d_out, int out_size, void* d_ws, size_t ws_size,
                              hipStream_t stream) {
  const float* feats        = (const float*)d_in[0];
  const float* inp_points   = (const float*)d_in[1];
  const float* out_points   = (const float*)d_in[2];
  const float* out_extents  = (const float*)d_in[3];
  const float* scale_compat = (const float*)d_in[4];
  const int*   nidx         = (const int*)d_in[5];
  const float* ndist        = (const float*)d_in[7];
  const float* kern         = (const float*)d_in[8];
  const float* bias         = (const float*)d_in[9];
  unsigned short* wf = (unsigned short*)d_ws;

  prep_w_kernel<<<(NTAP * CIN * COUT + 255) / 256, 256, 0, stream>>>(kern, wf);
  cconv_kernel<<<NOUT / GP, 512, 0, stream>>>(feats, inp_points, out_points,
                                              out_extents, scale_compat, nidx,
                                              ndist, wf, bias, (float*)d_out);
}

// Round 5
// 68.763 us; speedup vs baseline: 1.5760x; 1.5760x over previous
//
#include <hip/hip_runtime.h>
#include <hip/hip_bf16.h>
#include <hip/hip_fp16.h>

#define NOUT 50000
#define KNB 32            // neighbors per output point
#define CIN 16
#define COUT 32
#define NTAP 64
#define GP 8              // points per block (2 per wave, 4 waves)
#define ROW2B 2064        // bytes per point row in s_bl: 64*16*2 (bf16) + 16 pad

typedef __attribute__((ext_vector_type(8))) short short8;
typedef __attribute__((ext_vector_type(4))) float f32x4;

__device__ __forceinline__ unsigned int pk2(float lo, float hi) {
  // two f32 -> packed bf16x2 (RNE), lo -> bits[15:0]
  union { __hip_bfloat162 h2; unsigned int u; } cv;
  cv.h2 = __float22bfloat162_rn(make_float2(lo, hi));
  return cv.u;
}
__device__ __forceinline__ unsigned int pkh(float lo, float hi) {
  union { __half2 h; unsigned int u; } cv;
  cv.h = __floats2half2_rn(lo, hi);
  return cv.u;
}
__device__ __forceinline__ unsigned int f2bf(float f) {
  unsigned int u = __float_as_uint(f);
  return (u + 0x7fffu + ((u >> 16) & 1u)) >> 16;
}

// Wf[s][g][n][j] = bf16(W[kc = s*32 + g*8 + j][n]) : GEMM2 B-frag order
__global__ void prep_w_kernel(const float* __restrict__ kern,
                              unsigned short* __restrict__ wf) {
  int idx = blockIdx.x * 256 + threadIdx.x;
  if (idx >= NTAP * CIN * COUT) return;  // 32768
  int j = idx & 7;
  int n = (idx >> 3) & 31;
  int g = (idx >> 8) & 3;
  int s = idx >> 10;
  int kc = s * 32 + g * 8 + j;
  wf[idx] = (unsigned short)f2bf(kern[kc * COUT + n]);
}

__launch_bounds__(256, 8)
__global__ void cconv_kernel(const float* __restrict__ feats,
                             const float* __restrict__ inp_points,
                             const float* __restrict__ out_points,
                             const float* __restrict__ out_extents,
                             const float* __restrict__ scale_compat,
                             const int* __restrict__ nidx,
                             const float* __restrict__ ndist,
                             const unsigned short* __restrict__ wf,
                             const float* __restrict__ bias,
                             float* __restrict__ out) {
  // bf16 B matrix; element (t,c) of point p at byte p*ROW2B + t*32 + c*2
  __shared__ __align__(16) char s_bl[GP * ROW2B];          // 16512 B
  __shared__ uint2 s_edp[GP * KNB];                        // 2048 B f16x2 (tx,ty),(tz,imp)
  __shared__ float s_cacc[GP][COUT];                       // 1024 B
  __shared__ float s_den[GP];                              // 32 B

  const int tid = threadIdx.x;
  const int wv = tid >> 6;
  const int lane = tid & 63;
  const int c = lane & 15;          // phase-2 frag index (tap-in-tile / chan row)
  const int g = lane >> 4;          // phase-2 edge group

  ((float*)s_cacc)[tid] = 0.0f;     // blockDim == GP*COUT == 256 exactly

  // ---- phase 0: hoisted gather. Addresses depend only on blockIdx, so issue
  // ALL phase-2 global loads now; their latency overlaps phase-1 compute. ----
  float fpre[2][8];
#pragma unroll
  for (int h = 0; h < 2; ++h) {
    const int pg = blockIdx.x * GP + wv * 2 + h;
#pragma unroll
    for (int j = 0; j < 8; ++j) {
      const int nb = nidx[pg * KNB + g * 8 + j];
      fpre[h][j] = feats[nb * CIN + c];
    }
  }

  // ---- phase 1: geometry; all 64 lanes active (2 points per wave) ----
  {
    const int h = lane >> 5;          // which of the wave's 2 points
    const int e = lane & 31;          // edge
    const int p = wv * 2 + h;         // point-in-block
    const int pg = blockIdx.x * GP + p;
    const int eg = pg * KNB + e;
    const int nb = nidx[eg];
    const float d = ndist[eg];
    float q = 1.0f - d * d;
    float w6 = q * q * q;
    w6 = fminf(fmaxf(w6, 0.0f), 1.0f);
    const float imp = scale_compat[eg] * w6;

    const float inv = 1.0f / (0.5f * out_extents[pg]);
    const float rx = (inp_points[nb * 3 + 0] - out_points[pg * 3 + 0]) * inv;
    const float ry = (inp_points[nb * 3 + 1] - out_points[pg * 3 + 1]) * inv;
    const float rz = (inp_points[nb * 3 + 2] - out_points[pg * 3 + 2]) * inv;
    const float r = sqrtf(rx * rx + ry * ry + rz * rz);
    const float linf = fmaxf(fabsf(rx), fmaxf(fabsf(ry), fabsf(rz)));
    const float sf = r / fmaxf(linf, 1e-12f);
    const float tx = fminf(fmaxf((rx * sf * 0.5f + 0.5f) * 3.0f, 0.0f), 3.0f);
    const float ty = fminf(fmaxf((ry * sf * 0.5f + 0.5f) * 3.0f, 0.0f), 3.0f);
    const float tz = fminf(fmaxf((rz * sf * 0.5f + 0.5f) * 3.0f, 0.0f), 3.0f);

    s_edp[p * KNB + e] = make_uint2(pkh(tx, ty), pkh(tz, imp));

    float dsum = imp;                 // reduce within each 32-lane half
#pragma unroll
    for (int m = 1; m < 32; m <<= 1) dsum += __shfl_xor(dsum, m);
    if (e == 0) s_den[p] = dsum;
  }
  // NO barrier: phase 2 reads only this wave's own s_edp rows (same-wave LDS
  // ops execute in order).

  // ---- phase 2: per-point GEMM1, transposed: D1T(16c x 64t) = Fe^T * W^T.
  // Pure VALU+LDS now (feats prefetched). Lane holds 4 consecutive CHANNELS
  // of one tap -> direct bf16 packing, no shuffles. ----
  {
    const float kyf = (float)(c >> 2);
    const float kzf = (float)(c & 3);
#pragma unroll
    for (int h = 0; h < 2; ++h) {
      const int p = wv * 2 + h;
      union { unsigned int u[4]; short8 v; } wfr0, wfr1, wfr2, wfr3, fef;
      float wprev0, wprev1, wprev2, wprev3, feprev;
#pragma unroll
      for (int j = 0; j < 8; ++j) {
        const uint2 ep = s_edp[p * KNB + g * 8 + j];
        union { unsigned int u; __half2 h2; } ua, ub;
        ua.u = ep.x; ub.u = ep.y;
        const float tx = __low2float(ua.h2), ty = __high2float(ua.h2);
        const float tz = __low2float(ub.h2), im = __high2float(ub.h2);
        const float f = fpre[h][j];
        const float hy = fmaxf(0.0f, 1.0f - fabsf(ty - kyf));
        const float hz = fmaxf(0.0f, 1.0f - fabsf(tz - kzf));
        const float m = hy * hz * im;
        const float w0 = fmaxf(0.0f, 1.0f - tx) * m;            // tx >= 0
        const float w1 = fmaxf(0.0f, 1.0f - fabsf(tx - 1.0f)) * m;
        const float w2 = fmaxf(0.0f, 1.0f - fabsf(tx - 2.0f)) * m;
        const float w3 = fmaxf(0.0f, tx - 2.0f) * m;            // tx <= 3
        if (j & 1) {
          wfr0.u[j >> 1] = pk2(wprev0, w0);
          wfr1.u[j >> 1] = pk2(wprev1, w1);
          wfr2.u[j >> 1] = pk2(wprev2, w2);
          wfr3.u[j >> 1] = pk2(wprev3, w3);
          fef.u[j >> 1] = pk2(feprev, f);
        } else {
          wprev0 = w0; wprev1 = w1; wprev2 = w2; wprev3 = w3; feprev = f;
        }
      }
      const f32x4 z = {0.f, 0.f, 0.f, 0.f};
      f32x4 d0 = __builtin_amdgcn_mfma_f32_16x16x32_bf16(fef.v, wfr0.v, z, 0, 0, 0);
      f32x4 d1 = __builtin_amdgcn_mfma_f32_16x16x32_bf16(fef.v, wfr1.v, z, 0, 0, 0);
      f32x4 d2 = __builtin_amdgcn_mfma_f32_16x16x32_bf16(fef.v, wfr2.v, z, 0, 0, 0);
      f32x4 d3 = __builtin_amdgcn_mfma_f32_16x16x32_bf16(fef.v, wfr3.v, z, 0, 0, 0);
      // lane holds chans {4g..4g+3} of tap (tile*16 + c); byte = t*32 + chan*2
      char* bp = s_bl + (unsigned)(p * ROW2B + c * 32 + g * 8);
      *(uint2*)(bp + 0 * 512) = make_uint2(pk2(d0[0], d0[1]), pk2(d0[2], d0[3]));
      *(uint2*)(bp + 1 * 512) = make_uint2(pk2(d1[0], d1[1]), pk2(d1[2], d1[3]));
      *(uint2*)(bp + 2 * 512) = make_uint2(pk2(d2[0], d2[1]), pk2(d2[2], d2[3]));
      *(uint2*)(bp + 3 * 512) = make_uint2(pk2(d3[0], d3[1]), pk2(d3[2], d3[3]));
    }
  }

  __syncthreads();

  // ---- phase 3: GEMM2. M-frame 16 (8 valid points), N = 32, K = 1024 over
  // 4 waves (8 ksteps of 32 each); A-frag is a raw b128 bf16 read. ----
  f32x4 acc0 = {0.f, 0.f, 0.f, 0.f}, acc1 = {0.f, 0.f, 0.f, 0.f};
  const int pl = lane & 15;          // A row (mod GP) / B col selector
  const int arow = pl & (GP - 1);    // only GP point-rows exist
  const int g4 = lane >> 4;
#pragma unroll
  for (int ss = 0; ss < 8; ++ss) {
    const int s = wv * 8 + ss;
    const short8 a = *(const short8*)(s_bl + arow * ROW2B + s * 64 + g4 * 16);
    const short8 b0 = *(const short8*)(wf + ((unsigned)((s * 4 + g4) * 32) + pl) * 8);
    const short8 b1 = *(const short8*)(wf + ((unsigned)((s * 4 + g4) * 32) + 16 + pl) * 8);
    acc0 = __builtin_amdgcn_mfma_f32_16x16x32_bf16(a, b0, acc0, 0, 0, 0);
    acc1 = __builtin_amdgcn_mfma_f32_16x16x32_bf16(a, b1, acc1, 0, 0, 0);
  }
#pragma unroll
  for (int j = 0; j < 4; ++j) {
    const int row = g4 * 4 + j;      // D row = point; rows >= GP are duplicates
    if (row < GP) {
      atomicAdd(&s_cacc[row][pl], acc0[j]);
      atomicAdd(&s_cacc[row][pl + 16], acc1[j]);
    }
  }

  __syncthreads();

  // ---- epilogue: normalize, bias, relu; 256 threads == 256 outputs ----
  {
    const int p = tid >> 5;
    const int dch = tid & 31;
    const float den = s_den[p];
    float v = ((float*)s_cacc)[tid] / (den > 0.0f ? den : 1.0f) + bias[dch];
    out[blockIdx.x * (GP * COUT) + tid] = fmaxf(v, 0.0f);
  }
}

extern "C" void kernel_launch(void* const* d_in, const int* in_sizes, int n_in,
                              void* d_out, int out_size, void* d_ws, size_t ws_size,
                              hipStream_t stream) {
  const float* feats        = (const float*)d_in[0];
  const float* inp_points   = (const float*)d_in[1];
  const float* out_points   = (const float*)d_in[2];
  const float* out_extents  = (const float*)d_in[3];
  const float* scale_compat = (const float*)d_in[4];
  const int*   nidx         = (const int*)d_in[5];
  const float* ndist        = (const float*)d_in[7];
  const float* kern         = (const float*)d_in[8];
  const float* bias         = (const float*)d_in[9];
  unsigned short* wf = (unsigned short*)d_ws;

  prep_w_kernel<<<(NTAP * CIN * COUT + 255) / 256, 256, 0, stream>>>(kern, wf);
  cconv_kernel<<<NOUT / GP, 256, 0, stream>>>(feats, inp_points, out_points,
                                              out_extents, scale_compat, nidx,
                                              ndist, wf, bias, (float*)d_out);
}